// Round 6
// baseline (2053.448 us; speedup 1.0000x reference)
//
#include <hip/hip_runtime.h>
#include <math.h>

#define N_NODES 100000
#define N_EDGES 1600000
#define D_IN 256
#define D_H 128
#define D_OUT 32
#define N_PAD 102400
#define NBK 782        // ceil(100000/128) target buckets of 128 nodes
#define NSL 16         // slice stride (13 used: src>>13)
#define NREG (NBK*NSL) // 12512 regions
#define CAPR 288       // region capacity (mean 168, +9 sigma)
#define CHUNK 4096     // edges per bucketA block

typedef long long ll;
typedef unsigned int uint;
typedef unsigned short ushort;
typedef short frag_ab __attribute__((ext_vector_type(8)));   // 8 bf16
typedef float frag_cd __attribute__((ext_vector_type(4)));   // 4 f32

__device__ __forceinline__ ushort f2bf(float f) {            // RNE fp32->bf16
    uint u = __float_as_uint(f);
    u += 0x7FFFu + ((u >> 16) & 1u);
    return (ushort)(u >> 16);
}
__device__ __forceinline__ float bfl(uint u) { return __uint_as_float(u << 16); }
__device__ __forceinline__ float bfh(uint u) { return __uint_as_float(u & 0xFFFF0000u); }
__device__ __forceinline__ uint packbf(float a, float b) {
    return (uint)f2bf(a) | ((uint)f2bf(b) << 16);
}

// ---------------- degree histogram ----------------
__global__ void k_count(const int* __restrict__ col, int* __restrict__ deg, int e) {
    int i = blockIdx.x * blockDim.x + threadIdx.x;
    if (i < e) atomicAdd(&deg[col[i]], 1);
}

__global__ void k_dinv(const int* __restrict__ deg, float* __restrict__ dinv, int n) {
    int i = blockIdx.x * 256 + threadIdx.x;
    if (i < n) dinv[i] = rsqrtf((float)(1 + deg[i]));
}

// ---------------- edge partition into (target-bucket, source-slice) regions ----------------
// region id = (col>>7)*16 + (row>>13); pair = (row<<7)|(col&127)
__global__ __launch_bounds__(256) void k_bucketA(const int* __restrict__ row,
                                                 const int* __restrict__ col,
                                                 int* __restrict__ rcur,
                                                 uint* __restrict__ pairs, int e) {
    __shared__ int cnt[NREG];  // 50 KB
    const int t = threadIdx.x;
    for (int i = t; i < NREG; i += 256) cnt[i] = 0;
    __syncthreads();
    const int base = blockIdx.x * CHUNK;
    int myrid[CHUNK / 256];
    uint mypair[CHUNK / 256];
#pragma unroll
    for (int j = 0; j < CHUNK / 256; j++) {
        int idx = base + t + j * 256;
        if (idx < e) {
            int r = row[idx], c = col[idx];
            int rid = (c >> 7) * NSL + (r >> 13);
            myrid[j] = rid;
            mypair[j] = ((uint)r << 7) | (uint)(c & 127);
            atomicAdd(&cnt[rid], 1);
        } else {
            myrid[j] = -1;
        }
    }
    __syncthreads();
    for (int i = t; i < NREG; i += 256) {
        int c = cnt[i];
        cnt[i] = (c > 0) ? atomicAdd(&rcur[i], c) : 0;  // region-relative start
    }
    __syncthreads();
#pragma unroll
    for (int j = 0; j < CHUNK / 256; j++) {
        int rid = myrid[j];
        if (rid >= 0) {
            int rel = atomicAdd(&cnt[rid], 1);
            if (rel < CAPR) pairs[rid * CAPR + rel] = mypair[j];
        }
    }
}

// ---------------- weight transpose+convert: w1t[n][k], w2t[n][k] bf16 ----------------
__global__ void k_prep_w(const float* __restrict__ W1, const float* __restrict__ W2,
                         ushort* __restrict__ w1t, ushort* __restrict__ w2t) {
    int i = blockIdx.x * 256 + threadIdx.x;
    if (i < D_IN * D_H) {
        int k = i >> 7, nn = i & 127;
        w1t[nn * D_IN + k] = f2bf(W1[i]);
    } else if (i < D_IN * D_H + D_H * D_OUT) {
        int j = i - D_IN * D_H;
        int k = j >> 5, nn = j & 31;
        w2t[nn * D_H + k] = f2bf(W2[j]);
    }
}

// ---------------- GEMM1: hxs = bf16( dinv * (x @ W1) ) ----------------
// block tile 128 nodes x 128 dims; x staged once in LDS (bf16), B in registers.
// wave w owns dims {w*32 + 2*lm + nt}; one barrier total.
#define XS_S 264  // row stride in shorts (256 + 8 pad)
__global__ __launch_bounds__(256, 2) void k_gemm1(const float* __restrict__ x,
                                                  const ushort* __restrict__ w1t,
                                                  const float* __restrict__ dinv,
                                                  uint* __restrict__ hxs_u, int n) {
    __shared__ ushort xs[128 * XS_S];  // 67.6 KB
    const int tid = threadIdx.x;
    const int w = tid >> 6, lane = tid & 63;
    const int lm = lane & 15, quad = lane >> 4;
    const int base = blockIdx.x * 128;

    // stage x (fp32 -> bf16), coalesced
#pragma unroll
    for (int t = 0; t < 32; t++) {
        int f = tid + 256 * t;           // 0..8191
        int r = f >> 6, c4 = f & 63;
        int gn = base + r;
        float4 v = (gn < n) ? ((const float4*)x)[(ll)gn * 64 + c4]
                            : make_float4(0.f, 0.f, 0.f, 0.f);
        *(uint2*)&xs[r * XS_S + c4 * 4] = make_uint2(packbf(v.x, v.y), packbf(v.z, v.w));
    }

    // B into registers: 16 frags (2 nt x 8 ks)
    frag_ab B[2][8];
#pragma unroll
    for (int nt = 0; nt < 2; nt++) {
        const ushort* wr = w1t + (w * 32 + 2 * lm + nt) * D_IN;
#pragma unroll
        for (int ks = 0; ks < 8; ks++)
            B[nt][ks] = *(const frag_ab*)&wr[ks * 32 + quad * 8];
    }

    frag_cd acc[8][2];
#pragma unroll
    for (int mt = 0; mt < 8; mt++)
#pragma unroll
        for (int nt = 0; nt < 2; nt++) acc[mt][nt] = (frag_cd){0.f, 0.f, 0.f, 0.f};

    __syncthreads();

#pragma unroll
    for (int ks = 0; ks < 8; ks++) {
#pragma unroll
        for (int mt = 0; mt < 8; mt++) {
            frag_ab a = *(const frag_ab*)&xs[(mt * 16 + lm) * XS_S + ks * 32 + quad * 8];
#pragma unroll
            for (int nt = 0; nt < 2; nt++)
                acc[mt][nt] = __builtin_amdgcn_mfma_f32_16x16x32_bf16(
                    a, B[nt][ks], acc[mt][nt], 0, 0, 0);
        }
    }

#pragma unroll
    for (int mt = 0; mt < 8; mt++) {
#pragma unroll
        for (int r = 0; r < 4; r++) {
            int node = base + mt * 16 + quad * 4 + r;
            if (node < n) {
                float dv = dinv[node];
                hxs_u[(ll)node * 64 + w * 16 + lm] =
                    packbf(acc[mt][0][r] * dv, acc[mt][1][r] * dv);
            }
        }
    }
}

// ---------------- layer-1 aggregation: bucket-resident LDS accumulators ----------------
// block owns 128 target nodes; sweeps 13 source slices in order (L2 window locality).
// wave w owns dims [32w, 32w+32); 8 edges per memory instruction; ds_add_f32 RMW.
__global__ __launch_bounds__(256, 2) void k_agg1(const uint2* __restrict__ hxs2,
                                                 const uint* __restrict__ hxs_u,
                                                 const uint* __restrict__ pairs,
                                                 const int* __restrict__ rcnt,
                                                 const float* __restrict__ dinv,
                                                 const float* __restrict__ b1,
                                                 uint* __restrict__ h_u, int n) {
    __shared__ float acc[128 * 128];  // 64 KB
    const int tid = threadIdx.x;
    const int w = tid >> 6, lane = tid & 63;
    const int g = lane >> 3, sub = lane & 7;
    const int b = blockIdx.x, node0 = b << 7;

    for (int i = tid; i < 4096; i += 256)
        ((float4*)acc)[i] = make_float4(0.f, 0.f, 0.f, 0.f);
    __syncthreads();

    for (int s = 0; s < 13; s++) {
        int rid = b * NSL + s;
        int cnt = min(rcnt[rid], CAPR);
        const uint* pr = pairs + rid * CAPR;
        for (int bs = 0; bs < cnt; bs += 64) {
            uint pl = (bs + lane < cnt) ? pr[bs + lane] : 0u;
            int m = min(64, cnt - bs);
            for (int j = 0; j < m; j += 8) {
                uint p = __shfl(pl, j + g);
                if (j + g < m) {
                    int src = (int)(p >> 7);
                    int loc = (int)(p & 127);
                    uint2 u = hxs2[(ll)src * 32 + w * 8 + sub];
                    float* a = &acc[loc * 128 + w * 32 + sub * 4];
                    atomicAdd(a + 0, bfl(u.x));
                    atomicAdd(a + 1, bfh(u.x));
                    atomicAdd(a + 2, bfl(u.y));
                    atomicAdd(a + 3, bfh(u.y));
                }
            }
        }
    }
    __syncthreads();

    // epilogue: self + dinv scale + bias + relu -> h (bf16)
    for (int f = tid; f < 8192; f += 256) {
        int ln = f >> 6, du = f & 63;
        int v = node0 + ln;
        if (v >= n) continue;
        uint su = hxs_u[(ll)v * 64 + du];
        float a0 = acc[ln * 128 + 2 * du] + bfl(su);
        float a1 = acc[ln * 128 + 2 * du + 1] + bfh(su);
        float dv = dinv[v];
        float2 bb = ((const float2*)b1)[du];
        h_u[(ll)v * 64 + du] = packbf(fmaxf(fmaf(dv, a0, bb.x), 0.f),
                                      fmaxf(fmaf(dv, a1, bb.y), 0.f));
    }
}

// ---------------- GEMM2 (LDS-free): hx2s = bf16( dinv * (h @ W2) ) ----------------
__global__ __launch_bounds__(256) void k_gemm2(const ushort* __restrict__ h,
                                               const ushort* __restrict__ w2t,
                                               const float* __restrict__ dinv,
                                               uint* __restrict__ hx2s_u, int n) {
    const int tid = threadIdx.x;
    const int wv = tid >> 6, lane = tid & 63;
    const int lm = lane & 15, quad = lane >> 4;
    const int base = blockIdx.x * 128 + wv * 32;

    frag_ab B[2][4];
#pragma unroll
    for (int nt = 0; nt < 2; nt++) {
        const ushort* wr = w2t + (2 * lm + nt) * D_H;
#pragma unroll
        for (int ks = 0; ks < 4; ks++)
            B[nt][ks] = *(const frag_ab*)&wr[ks * 32 + quad * 8];
    }

    frag_cd acc[2][2];
#pragma unroll
    for (int mt = 0; mt < 2; mt++)
#pragma unroll
        for (int nt = 0; nt < 2; nt++) acc[mt][nt] = (frag_cd){0.f, 0.f, 0.f, 0.f};

    const ushort* hr[2];
#pragma unroll
    for (int mt = 0; mt < 2; mt++) {
        int node = base + mt * 16 + lm;
        hr[mt] = h + (ll)min(node, n - 1) * D_H;
    }

#pragma unroll
    for (int ks = 0; ks < 4; ks++) {
        frag_ab a[2];
#pragma unroll
        for (int mt = 0; mt < 2; mt++)
            a[mt] = *(const frag_ab*)&hr[mt][ks * 32 + quad * 8];
#pragma unroll
        for (int mt = 0; mt < 2; mt++)
#pragma unroll
            for (int nt = 0; nt < 2; nt++)
                acc[mt][nt] = __builtin_amdgcn_mfma_f32_16x16x32_bf16(
                    a[mt], B[nt][ks], acc[mt][nt], 0, 0, 0);
    }

#pragma unroll
    for (int mt = 0; mt < 2; mt++) {
#pragma unroll
        for (int r = 0; r < 4; r++) {
            int node = base + mt * 16 + quad * 4 + r;
            if (node < n) {
                float dv = dinv[node];
                hx2s_u[(ll)node * 16 + lm] =
                    packbf(acc[mt][0][r] * dv, acc[mt][1][r] * dv);
            }
        }
    }
}

// ---------------- layer-2 aggregation + bias + log_softmax ----------------
// same bucket/slice structure; wave w owns dims [8w, 8w+8); 32 edges per instr.
__global__ __launch_bounds__(256) void k_agg2(const uint2* __restrict__ hx2s2,
                                              const uint* __restrict__ pairs,
                                              const int* __restrict__ rcnt,
                                              const float* __restrict__ dinv,
                                              const float* __restrict__ b2,
                                              float4* __restrict__ out, int n) {
    __shared__ float acc[128 * 32];  // 16 KB
    const int tid = threadIdx.x;
    const int w = tid >> 6, lane = tid & 63;
    const int g = lane >> 1, sub = lane & 1;
    const int b = blockIdx.x, node0 = b << 7;

    for (int i = tid; i < 1024; i += 256)
        ((float4*)acc)[i] = make_float4(0.f, 0.f, 0.f, 0.f);
    __syncthreads();

    for (int s = 0; s < 13; s++) {
        int rid = b * NSL + s;
        int cnt = min(rcnt[rid], CAPR);
        const uint* pr = pairs + rid * CAPR;
        for (int bs = 0; bs < cnt; bs += 64) {
            uint pl = (bs + lane < cnt) ? pr[bs + lane] : 0u;
            int m = min(64, cnt - bs);
            for (int j = 0; j < m; j += 32) {
                uint p = __shfl(pl, j + g);
                if (j + g < m) {
                    int src = (int)(p >> 7);
                    int loc = (int)(p & 127);
                    uint2 u = hx2s2[(ll)src * 8 + w * 2 + sub];
                    float* a = &acc[loc * 32 + w * 8 + sub * 4];
                    atomicAdd(a + 0, bfl(u.x));
                    atomicAdd(a + 1, bfh(u.x));
                    atomicAdd(a + 2, bfl(u.y));
                    atomicAdd(a + 3, bfh(u.y));
                }
            }
        }
    }
    __syncthreads();

    // epilogue: self + dinv + bias + log_softmax (8 lanes per node, 4 dims each)
    for (int base2 = 0; base2 < 128; base2 += 32) {
        int ln = base2 + (tid >> 3), l = tid & 7;
        int v = node0 + ln;
        if (v < n) {
            float4 a = *(float4*)&acc[ln * 32 + l * 4];
            uint2 su = hx2s2[(ll)v * 8 + l];
            a.x += bfl(su.x); a.y += bfh(su.x); a.z += bfl(su.y); a.w += bfh(su.y);
            float dv = dinv[v];
            float4 bb = ((const float4*)b2)[l];
            float t0 = fmaf(dv, a.x, bb.x), t1 = fmaf(dv, a.y, bb.y);
            float t2 = fmaf(dv, a.z, bb.z), t3 = fmaf(dv, a.w, bb.w);
            float mx = fmaxf(fmaxf(t0, t1), fmaxf(t2, t3));
#pragma unroll
            for (int msk = 4; msk >= 1; msk >>= 1) mx = fmaxf(mx, __shfl_xor(mx, msk));
            float sum = __expf(t0 - mx) + __expf(t1 - mx) + __expf(t2 - mx) + __expf(t3 - mx);
#pragma unroll
            for (int msk = 4; msk >= 1; msk >>= 1) sum += __shfl_xor(sum, msk);
            float lse = mx + __logf(sum);
            out[(ll)v * 8 + l] = make_float4(t0 - lse, t1 - lse, t2 - lse, t3 - lse);
        }
    }
}

extern "C" void kernel_launch(void* const* d_in, const int* in_sizes, int n_in,
                              void* d_out, int out_size, void* d_ws, size_t ws_size,
                              hipStream_t stream) {
    const float* x  = (const float*)d_in[0];
    const float* W1 = (const float*)d_in[1];
    const float* b1 = (const float*)d_in[2];
    const float* W2 = (const float*)d_in[3];
    const float* b2 = (const float*)d_in[4];
    const int*   ei = (const int*)d_in[5];
    const int* row = ei;
    const int* col = ei + N_EDGES;

    // ws layout (4B words): deg[N_PAD] | rcur[NREG] | dinv[N_PAD] | pairs[NREG*CAPR] |
    //   w1t(bf16 32768) | w2t(bf16 4096) | hxs(bf16 N*128) | h(bf16 N*128) | hx2s(bf16 N*32)
    int*    ws_i  = (int*)d_ws;
    int*    deg   = ws_i;
    int*    rcur  = ws_i + N_PAD;
    float*  dinv  = (float*)(ws_i + N_PAD + NREG);
    uint*   pairs = (uint*)(ws_i + 2 * N_PAD + NREG);
    ushort* w1t   = (ushort*)(pairs + NREG * CAPR);
    ushort* w2t   = w1t + D_IN * D_H;
    ushort* hxs   = w2t + D_H * D_OUT;
    ushort* h     = hxs + (ll)N_NODES * D_H;
    ushort* hx2s  = h + (ll)N_NODES * D_H;

    const int n = N_NODES, e = N_EDGES;

    hipMemsetAsync(deg, 0, (N_PAD + NREG) * sizeof(int), stream);
    k_count<<<(e + 255) / 256, 256, 0, stream>>>(col, deg, e);
    k_dinv<<<(n + 255) / 256, 256, 0, stream>>>(deg, dinv, n);
    k_bucketA<<<(e + CHUNK - 1) / CHUNK, 256, 0, stream>>>(row, col, rcur, pairs, e);
    k_prep_w<<<(D_IN * D_H + D_H * D_OUT + 255) / 256, 256, 0, stream>>>(W1, W2, w1t, w2t);

    k_gemm1<<<NBK, 256, 0, stream>>>(x, w1t, dinv, (uint*)hxs, n);
    k_agg1<<<NBK, 256, 0, stream>>>((const uint2*)hxs, (const uint*)hxs, pairs, rcur,
                                    dinv, b1, (uint*)h, n);
    k_gemm2<<<NBK, 256, 0, stream>>>(h, w2t, dinv, (uint*)hx2s, n);
    k_agg2<<<NBK, 256, 0, stream>>>((const uint2*)hx2s, pairs, rcur, dinv, b2,
                                    (float4*)d_out, n);
}

// Round 7
// 431.502 us; speedup vs baseline: 4.7588x; 4.7588x over previous
//
#include <hip/hip_runtime.h>
#include <math.h>

#define N_NODES 100000
#define N_EDGES 1600000
#define D_IN 256
#define D_H 128
#define D_OUT 32
#define N_PAD 102400
#define NB 196       // ceil(100000/512) buckets of 512 target nodes
#define CAPB 10240   // fixed capacity per bucket (mean 8192, +22 sigma)
#define CHUNK 4096   // edges per bucketA block

typedef long long ll;
typedef unsigned int uint;
typedef unsigned short ushort;
typedef short frag_ab __attribute__((ext_vector_type(8)));   // 8 bf16
typedef float frag_cd __attribute__((ext_vector_type(4)));   // 4 f32

__device__ __forceinline__ ushort f2bf(float f) {            // RNE fp32->bf16
    uint u = __float_as_uint(f);
    u += 0x7FFFu + ((u >> 16) & 1u);
    return (ushort)(u >> 16);
}
__device__ __forceinline__ float bfl(uint u) { return __uint_as_float(u << 16); }
__device__ __forceinline__ float bfh(uint u) { return __uint_as_float(u & 0xFFFF0000u); }
__device__ __forceinline__ uint packbf(float a, float b) {
    return (uint)f2bf(a) | ((uint)f2bf(b) << 16);
}

// ---------------- pass A: deg histogram + bucket partition (fixed-cap regions) ----------
// pair = (row<<9) | (col&511); bucket = col>>9
__global__ __launch_bounds__(256) void k_bucketA(const int* __restrict__ row,
                                                 const int* __restrict__ col,
                                                 int* __restrict__ deg,
                                                 int* __restrict__ gcur,
                                                 uint* __restrict__ pairs, int e) {
    __shared__ int cnt[NB];
    __shared__ int lstart[NB];
    const int t = threadIdx.x;
    for (int i = t; i < NB; i += 256) cnt[i] = 0;
    __syncthreads();
    const int base = blockIdx.x * CHUNK;
    uint mypair[CHUNK / 256];
    int myb[CHUNK / 256];
#pragma unroll
    for (int j = 0; j < CHUNK / 256; j++) {
        int idx = base + t + j * 256;
        if (idx < e) {
            int r = row[idx], c = col[idx];
            atomicAdd(&deg[c], 1);
            myb[j] = c >> 9;
            mypair[j] = ((uint)r << 9) | (uint)(c & 511);
            atomicAdd(&cnt[c >> 9], 1);
        } else {
            myb[j] = -1;
        }
    }
    __syncthreads();
    for (int i = t; i < NB; i += 256) {
        int c = cnt[i];
        lstart[i] = (c > 0) ? atomicAdd(&gcur[i], c) : 0;
        cnt[i] = 0;  // reuse as local cursor
    }
    __syncthreads();
#pragma unroll
    for (int j = 0; j < CHUNK / 256; j++) {
        int b = myb[j];
        if (b >= 0) {
            int rel = lstart[b] + atomicAdd(&cnt[b], 1);
            if (rel < CAPB) pairs[b * CAPB + rel] = mypair[j];
        }
    }
}

// ---------------- exclusive scan of deg -> rp ----------------
__global__ void k_scan1(const int* __restrict__ deg, int* __restrict__ rp,
                        int* __restrict__ bsum, int n) {
    __shared__ int s[256];
    int i = blockIdx.x * 256 + threadIdx.x;
    int v = (i < n) ? deg[i] : 0;
    s[threadIdx.x] = v;
    __syncthreads();
    for (int off = 1; off < 256; off <<= 1) {
        int t = (threadIdx.x >= off) ? s[threadIdx.x - off] : 0;
        __syncthreads();
        s[threadIdx.x] += t;
        __syncthreads();
    }
    if (i < n) rp[i] = s[threadIdx.x] - v;
    if (threadIdx.x == 255) bsum[blockIdx.x] = s[255];
}

__global__ void k_scan2(int* __restrict__ bsum, int nb) {
    __shared__ int s[512];
    int v = (threadIdx.x < nb) ? bsum[threadIdx.x] : 0;
    s[threadIdx.x] = v;
    __syncthreads();
    for (int off = 1; off < 512; off <<= 1) {
        int t = (threadIdx.x >= off) ? s[threadIdx.x - off] : 0;
        __syncthreads();
        s[threadIdx.x] += t;
        __syncthreads();
    }
    if (threadIdx.x < nb) bsum[threadIdx.x] = s[threadIdx.x] - v;
}

// rp += block offset; cursor = rp; dinv = rsqrt(1+deg)
__global__ void k_finalize(int* __restrict__ rp, const int* __restrict__ bsum,
                           const int* __restrict__ deg, int* __restrict__ cursor,
                           float* __restrict__ dinv, int n) {
    int i = blockIdx.x * 256 + threadIdx.x;
    if (i < n) {
        int r = rp[i] + bsum[i >> 8];
        rp[i] = r;
        cursor[i] = r;
        dinv[i] = rsqrtf((float)(1 + deg[i]));
    }
}

// ---------------- pass B: parallel CSR fill (4 blocks per bucket) ----------------
__global__ __launch_bounds__(256) void k_fillpar(const uint* __restrict__ pairs,
                                                 const int* __restrict__ gcur,
                                                 int* __restrict__ cursor,
                                                 int* __restrict__ csr_src) {
    const int b = blockIdx.x >> 2, p = blockIdx.x & 3;
    const int cnt = min(gcur[b], CAPB);
    const int chunk = (cnt + 3) >> 2;
    const int s = p * chunk, t_end = min(s + chunk, cnt);
    const int node0 = b << 9;
    const uint* pr = pairs + b * CAPB;
    for (int i = s + threadIdx.x; i < t_end; i += 256) {
        uint pp = pr[i];
        int node = node0 + (int)(pp & 511);
        int pos = atomicAdd(&cursor[node], 1);
        csr_src[pos] = (int)(pp >> 9);
    }
}

// ---------------- weight transpose+convert: w1t[n][k], w2t[n][k] bf16 ----------------
__global__ void k_prep_w(const float* __restrict__ W1, const float* __restrict__ W2,
                         ushort* __restrict__ w1t, ushort* __restrict__ w2t) {
    int i = blockIdx.x * 256 + threadIdx.x;
    if (i < D_IN * D_H) {
        int k = i >> 7, nn = i & 127;
        w1t[nn * D_IN + k] = f2bf(W1[i]);
    } else if (i < D_IN * D_H + D_H * D_OUT) {
        int j = i - D_IN * D_H;
        int k = j >> 5, nn = j & 31;
        w2t[nn * D_H + k] = f2bf(W2[j]);
    }
}

// ---------------- GEMM1 (MFMA, LDS-free): hxs = bf16( dinv * (x @ W1) ) ----------------
// wave = 32 nodes x 128 dims; block = 4 waves = 128 nodes; no barriers.
__global__ __launch_bounds__(256, 3) void k_gemm1(const float* __restrict__ x,
                                                  const ushort* __restrict__ w1t,
                                                  const float* __restrict__ dinv,
                                                  ushort* __restrict__ hxs, int n) {
    const int tid = threadIdx.x;
    const int wv = tid >> 6, lane = tid & 63;
    const int lm = lane & 15, quad = lane >> 4;
    const int base = blockIdx.x * 128 + wv * 32;

    frag_cd acc[2][8];
#pragma unroll
    for (int mt = 0; mt < 2; mt++)
#pragma unroll
        for (int nt = 0; nt < 8; nt++) acc[mt][nt] = (frag_cd){0.f, 0.f, 0.f, 0.f};

    const float4* xr[2];
#pragma unroll
    for (int mt = 0; mt < 2; mt++) {
        int node = base + mt * 16 + lm;
        xr[mt] = (const float4*)(x + (ll)min(node, n - 1) * D_IN);
    }

#pragma unroll
    for (int ks = 0; ks < 8; ks++) {       // K = 256 in chunks of 32
        frag_ab a[2];
#pragma unroll
        for (int mt = 0; mt < 2; mt++) {
            float4 v0 = xr[mt][ks * 8 + quad * 2];
            float4 v1 = xr[mt][ks * 8 + quad * 2 + 1];
            uint* ap = (uint*)&a[mt];
            ap[0] = packbf(v0.x, v0.y);
            ap[1] = packbf(v0.z, v0.w);
            ap[2] = packbf(v1.x, v1.y);
            ap[3] = packbf(v1.z, v1.w);
        }
#pragma unroll
        for (int nt = 0; nt < 8; nt++) {
            frag_ab b = *(const frag_ab*)&w1t[(nt * 16 + lm) * D_IN + ks * 32 + quad * 8];
#pragma unroll
            for (int mt = 0; mt < 2; mt++)
                acc[mt][nt] = __builtin_amdgcn_mfma_f32_16x16x32_bf16(
                    a[mt], b, acc[mt][nt], 0, 0, 0);
        }
    }

#pragma unroll
    for (int mt = 0; mt < 2; mt++) {
#pragma unroll
        for (int r = 0; r < 4; r++) {
            int node = base + mt * 16 + quad * 4 + r;
            if (node < n) {
                float dv = dinv[node];
#pragma unroll
                for (int nt = 0; nt < 8; nt++)
                    hxs[(ll)node * D_H + nt * 16 + lm] = f2bf(acc[mt][nt][r] * dv);
            }
        }
    }
}

// ---------------- layer-1 gather (bf16 rows): one wave per node ----------------
__global__ __launch_bounds__(256) void k_agg1(const uint* __restrict__ hxs,
                                              const int* __restrict__ csr_src,
                                              const int* __restrict__ rp,
                                              const int* __restrict__ deg,
                                              const float* __restrict__ dinv,
                                              const float* __restrict__ b1,
                                              uint* __restrict__ h, int n) {
    int v = blockIdx.x * 4 + (threadIdx.x >> 6);
    if (v >= n) return;
    int lane = threadIdx.x & 63;
    uint u = hxs[v * 64 + lane];
    float a0 = bfl(u), a1 = bfh(u);
    int s = rp[v], e = s + deg[v];
    int i = s;
    for (; i + 7 < e; i += 8) {
        int s0 = csr_src[i], s1 = csr_src[i + 1];
        int s2 = csr_src[i + 2], s3 = csr_src[i + 3];
        int s4 = csr_src[i + 4], s5 = csr_src[i + 5];
        int s6 = csr_src[i + 6], s7 = csr_src[i + 7];
        uint u0 = hxs[s0 * 64 + lane], u1 = hxs[s1 * 64 + lane];
        uint u2 = hxs[s2 * 64 + lane], u3 = hxs[s3 * 64 + lane];
        uint u4 = hxs[s4 * 64 + lane], u5 = hxs[s5 * 64 + lane];
        uint u6 = hxs[s6 * 64 + lane], u7 = hxs[s7 * 64 + lane];
        a0 += bfl(u0) + bfl(u1) + bfl(u2) + bfl(u3) + bfl(u4) + bfl(u5) + bfl(u6) + bfl(u7);
        a1 += bfh(u0) + bfh(u1) + bfh(u2) + bfh(u3) + bfh(u4) + bfh(u5) + bfh(u6) + bfh(u7);
    }
    for (; i + 1 < e; i += 2) {
        int s0 = csr_src[i], s1 = csr_src[i + 1];
        uint u0 = hxs[s0 * 64 + lane], u1 = hxs[s1 * 64 + lane];
        a0 += bfl(u0) + bfl(u1);
        a1 += bfh(u0) + bfh(u1);
    }
    if (i < e) {
        uint u0 = hxs[csr_src[i] * 64 + lane];
        a0 += bfl(u0);
        a1 += bfh(u0);
    }
    float dv = dinv[v];
    float2 bb = ((const float2*)b1)[lane];
    h[v * 64 + lane] = packbf(fmaxf(fmaf(dv, a0, bb.x), 0.f),
                              fmaxf(fmaf(dv, a1, bb.y), 0.f));
}

// ---------------- GEMM2 (MFMA, LDS-free): hx2s = bf16( dinv * (h @ W2) ) ----------------
__global__ __launch_bounds__(256) void k_gemm2(const ushort* __restrict__ h,
                                               const ushort* __restrict__ w2t,
                                               const float* __restrict__ dinv,
                                               ushort* __restrict__ hx2s, int n) {
    const int tid = threadIdx.x;
    const int wv = tid >> 6, lane = tid & 63;
    const int lm = lane & 15, quad = lane >> 4;
    const int base = blockIdx.x * 128 + wv * 32;

    frag_cd acc[2][2];
#pragma unroll
    for (int mt = 0; mt < 2; mt++)
#pragma unroll
        for (int nt = 0; nt < 2; nt++) acc[mt][nt] = (frag_cd){0.f, 0.f, 0.f, 0.f};

    const ushort* hr[2];
#pragma unroll
    for (int mt = 0; mt < 2; mt++) {
        int node = base + mt * 16 + lm;
        hr[mt] = h + (ll)min(node, n - 1) * D_H;
    }

#pragma unroll
    for (int ks = 0; ks < 4; ks++) {       // K = 128 in chunks of 32
        frag_ab a[2], b[2];
#pragma unroll
        for (int mt = 0; mt < 2; mt++)
            a[mt] = *(const frag_ab*)&hr[mt][ks * 32 + quad * 8];
#pragma unroll
        for (int nt = 0; nt < 2; nt++)
            b[nt] = *(const frag_ab*)&w2t[(nt * 16 + lm) * D_H + ks * 32 + quad * 8];
#pragma unroll
        for (int mt = 0; mt < 2; mt++)
#pragma unroll
            for (int nt = 0; nt < 2; nt++)
                acc[mt][nt] = __builtin_amdgcn_mfma_f32_16x16x32_bf16(
                    a[mt], b[nt], acc[mt][nt], 0, 0, 0);
    }

#pragma unroll
    for (int mt = 0; mt < 2; mt++) {
#pragma unroll
        for (int r = 0; r < 4; r++) {
            int node = base + mt * 16 + quad * 4 + r;
            if (node < n) {
                float dv = dinv[node];
#pragma unroll
                for (int nt = 0; nt < 2; nt++)
                    hx2s[(ll)node * D_OUT + nt * 16 + lm] = f2bf(acc[mt][nt][r] * dv);
            }
        }
    }
}

// ---------------- layer-2 gather + bias + log_softmax: 16 lanes per node ----------------
__global__ __launch_bounds__(256) void k_agg2(const uint* __restrict__ hx2s,
                                              const int* __restrict__ csr_src,
                                              const int* __restrict__ rp,
                                              const int* __restrict__ deg,
                                              const float* __restrict__ dinv,
                                              const float* __restrict__ b2,
                                              float2* __restrict__ out, int n) {
    int v = blockIdx.x * 16 + (threadIdx.x >> 4);
    if (v >= n) return;
    int l16 = threadIdx.x & 15;
    uint u = hx2s[v * 16 + l16];
    float a0 = bfl(u), a1 = bfh(u);
    int s = rp[v], e = s + deg[v];
    int i = s;
    for (; i + 7 < e; i += 8) {
        int s0 = csr_src[i], s1 = csr_src[i + 1];
        int s2 = csr_src[i + 2], s3 = csr_src[i + 3];
        int s4 = csr_src[i + 4], s5 = csr_src[i + 5];
        int s6 = csr_src[i + 6], s7 = csr_src[i + 7];
        uint u0 = hx2s[s0 * 16 + l16], u1 = hx2s[s1 * 16 + l16];
        uint u2 = hx2s[s2 * 16 + l16], u3 = hx2s[s3 * 16 + l16];
        uint u4 = hx2s[s4 * 16 + l16], u5 = hx2s[s5 * 16 + l16];
        uint u6 = hx2s[s6 * 16 + l16], u7 = hx2s[s7 * 16 + l16];
        a0 += bfl(u0) + bfl(u1) + bfl(u2) + bfl(u3) + bfl(u4) + bfl(u5) + bfl(u6) + bfl(u7);
        a1 += bfh(u0) + bfh(u1) + bfh(u2) + bfh(u3) + bfh(u4) + bfh(u5) + bfh(u6) + bfh(u7);
    }
    for (; i + 1 < e; i += 2) {
        int s0 = csr_src[i], s1 = csr_src[i + 1];
        uint u0 = hx2s[s0 * 16 + l16], u1 = hx2s[s1 * 16 + l16];
        a0 += bfl(u0) + bfl(u1);
        a1 += bfh(u0) + bfh(u1);
    }
    if (i < e) {
        uint u0 = hx2s[csr_src[i] * 16 + l16];
        a0 += bfl(u0);
        a1 += bfh(u0);
    }
    float dv = dinv[v];
    float2 bb = ((const float2*)b2)[l16];
    float t0 = fmaf(dv, a0, bb.x), t1 = fmaf(dv, a1, bb.y);
    float mx = fmaxf(t0, t1);
#pragma unroll
    for (int m = 8; m >= 1; m >>= 1) mx = fmaxf(mx, __shfl_xor(mx, m));
    float sum = __expf(t0 - mx) + __expf(t1 - mx);
#pragma unroll
    for (int m = 8; m >= 1; m >>= 1) sum += __shfl_xor(sum, m);
    float lse = mx + __logf(sum);
    out[v * 16 + l16] = make_float2(t0 - lse, t1 - lse);
}

extern "C" void kernel_launch(void* const* d_in, const int* in_sizes, int n_in,
                              void* d_out, int out_size, void* d_ws, size_t ws_size,
                              hipStream_t stream) {
    const float* x  = (const float*)d_in[0];
    const float* W1 = (const float*)d_in[1];
    const float* b1 = (const float*)d_in[2];
    const float* W2 = (const float*)d_in[3];
    const float* b2 = (const float*)d_in[4];
    const int*   ei = (const int*)d_in[5];
    const int* row = ei;
    const int* col = ei + N_EDGES;

    // ws layout (4B words): deg[N_PAD] | gcur[256] | rp[N_PAD] | bsum[512] | cursor[N_PAD] |
    //   dinv[N_PAD] | csr_src[E] | pairs[NB*CAPB] | w1t | w2t | hxs | h | hx2s
    int*    ws_i    = (int*)d_ws;
    int*    deg     = ws_i;
    int*    gcur    = ws_i + N_PAD;
    int*    rp      = ws_i + N_PAD + 256;
    int*    bsum    = ws_i + 2 * N_PAD + 256;
    int*    cursor  = ws_i + 2 * N_PAD + 768;
    float*  dinv    = (float*)(ws_i + 3 * N_PAD + 768);
    int*    csr_src = ws_i + 4 * N_PAD + 768;
    uint*   pairs   = (uint*)(csr_src + N_EDGES);
    ushort* w1t     = (ushort*)(pairs + NB * CAPB);
    ushort* w2t     = w1t + D_IN * D_H;
    ushort* hxs     = w2t + D_H * D_OUT;
    ushort* h       = hxs + (ll)N_NODES * D_H;
    ushort* hx2s    = h + (ll)N_NODES * D_H;

    const int n = N_NODES, e = N_EDGES;
    const int nb = (n + 255) / 256;

    hipMemsetAsync(deg, 0, (N_PAD + 256) * sizeof(int), stream);  // deg + gcur
    k_bucketA<<<(e + CHUNK - 1) / CHUNK, 256, 0, stream>>>(row, col, deg, gcur, pairs, e);
    k_scan1<<<nb, 256, 0, stream>>>(deg, rp, bsum, n);
    k_scan2<<<1, 512, 0, stream>>>(bsum, nb);
    k_finalize<<<nb, 256, 0, stream>>>(rp, bsum, deg, cursor, dinv, n);
    k_fillpar<<<NB * 4, 256, 0, stream>>>(pairs, gcur, cursor, csr_src);
    k_prep_w<<<(D_IN * D_H + D_H * D_OUT + 255) / 256, 256, 0, stream>>>(W1, W2, w1t, w2t);

    k_gemm1<<<(n + 127) / 128, 256, 0, stream>>>(x, w1t, dinv, hxs, n);
    k_agg1<<<(n + 3) / 4, 256, 0, stream>>>((const uint*)hxs, csr_src, rp, deg, dinv, b1,
                                            (uint*)h, n);
    k_gemm2<<<(n + 127) / 128, 256, 0, stream>>>(h, w2t, dinv, hx2s, n);
    k_agg2<<<(n + 15) / 16, 256, 0, stream>>>((const uint*)hx2s, csr_src, rp, deg, dinv, b2,
                                              (float2*)d_out, n);
}